// Round 4
// baseline (73.230 us; speedup 1.0000x reference)
//
#include <hip/hip_runtime.h>

// NFP pooling: out[b,o,i,j] = -sum_c |x[b,c,i+1,j+1] - x[b,c,i+di,j+dj]|
// for the 8 non-center (di,dj) in a 3x3 window. x: (8,128,224,224) f32.
// out: (8,8,222,222) f32.
//
// R4: TLP fix. 6 output cols/thread (2x float4 per row), 4-way channel
// split (chunk = wave in block, 32 ch each), LDS combine. 1027 blocks ->
// 4 blocks/CU -> 16 waves/CU (vs 12 before), 1 load-instr per output
// (vs 3). Latency-bound diagnosis per R2 counters.

constexpr int C  = 128;
constexpr int H  = 224;
constexpr int W  = 224;
constexpr int HO = 222;
constexpr int WO = 222;
constexpr int GPR_ = 37;                    // 6-col groups per output row
constexpr int PLANE = H * W;                // 50176
constexpr int OPLANE = HO * WO;             // 49284
constexpr int TOTALG = 8 * HO * GPR_;       // 65712 groups
constexpr int GPB = 64;                     // groups per block
constexpr int NBLK = (TOTALG + GPB - 1) / GPB;  // 1027
constexpr int CH = 32;                      // channels per chunk
constexpr int RSTRIDE = 145;                // 3*48+1, odd -> conflict-free

#define LOAD6(X0, X1, Y0, Y1, Z0, Z1, ptr)                             \
    X0 = *reinterpret_cast<const float4*>(ptr);                        \
    X1 = *reinterpret_cast<const float4*>((ptr) + 4);                  \
    Y0 = *reinterpret_cast<const float4*>((ptr) + W);                  \
    Y1 = *reinterpret_cast<const float4*>((ptr) + W + 4);              \
    Z0 = *reinterpret_cast<const float4*>((ptr) + 2 * W);              \
    Z1 = *reinterpret_cast<const float4*>((ptr) + 2 * W + 4);

// offset order: (0,0),(0,1),(0,2),(1,0),(1,2),(2,0),(2,1),(2,2)
// acc[o*6+q]; shared horizontal diffs hh[m]=|y[m+1]-y[m]|: o3(q)=hh[q], o4(q)=hh[q+1]
#define COMP(X0, X1, Y0, Y1, Z0, Z1) {                                 \
    const float xv[8] = {X0.x, X0.y, X0.z, X0.w, X1.x, X1.y, X1.z, X1.w}; \
    const float yv[8] = {Y0.x, Y0.y, Y0.z, Y0.w, Y1.x, Y1.y, Y1.z, Y1.w}; \
    const float zv[8] = {Z0.x, Z0.y, Z0.z, Z0.w, Z1.x, Z1.y, Z1.z, Z1.w}; \
    float hh[7];                                                       \
    _Pragma("unroll")                                                  \
    for (int m = 0; m < 7; ++m) hh[m] = __builtin_fabsf(yv[m + 1] - yv[m]); \
    _Pragma("unroll")                                                  \
    for (int q = 0; q < 6; ++q) {                                      \
        float ctr = yv[q + 1];                                         \
        acc[0 * 6 + q] += __builtin_fabsf(ctr - xv[q]);                \
        acc[1 * 6 + q] += __builtin_fabsf(ctr - xv[q + 1]);            \
        acc[2 * 6 + q] += __builtin_fabsf(ctr - xv[q + 2]);            \
        acc[3 * 6 + q] += hh[q];                                       \
        acc[4 * 6 + q] += hh[q + 1];                                   \
        acc[5 * 6 + q] += __builtin_fabsf(ctr - zv[q]);                \
        acc[6 * 6 + q] += __builtin_fabsf(ctr - zv[q + 1]);            \
        acc[7 * 6 + q] += __builtin_fabsf(ctr - zv[q + 2]);            \
    }                                                                  \
}

__global__ __launch_bounds__(256, 1)
void nfp_sad_kernel(const float* __restrict__ x, float* __restrict__ out) {
    __shared__ float red[GPB * RSTRIDE];    // 37.1 KB

    int tid = threadIdx.x;
    int g = tid & 63;                       // group within block
    int chunk = tid >> 6;                   // channel chunk = wave id
    int G = blockIdx.x * GPB + g;
    bool act = G < TOTALG;

    int b  = G / (HO * GPR_);
    int rem = G % (HO * GPR_);
    int i  = rem / GPR_;                    // output row
    int gc = rem % GPR_;                    // col group: output cols 6gc..6gc+5

    float acc[48];
#pragma unroll
    for (int k = 0; k < 48; ++k) acc[k] = 0.0f;

    if (act) {
        // input rows i..i+2, cols 6gc..6gc+7 (max 223, in-bounds)
        const float* p = x + ((size_t)b * C + chunk * CH) * PLANE
                           + (size_t)i * W + 6 * gc;

        float4 Ax0, Ax1, Ay0, Ay1, Az0, Az1;
        float4 Bx0, Bx1, By0, By1, Bz0, Bz1;

        LOAD6(Ax0, Ax1, Ay0, Ay1, Az0, Az1, p); p += PLANE;     // c0
        for (int k = 0; k < (CH - 2) / 2; ++k) {                // 15 iters
            LOAD6(Bx0, Bx1, By0, By1, Bz0, Bz1, p); p += PLANE; // c 2k+1
            COMP(Ax0, Ax1, Ay0, Ay1, Az0, Az1);                 // c 2k
            LOAD6(Ax0, Ax1, Ay0, Ay1, Az0, Az1, p); p += PLANE; // c 2k+2
            COMP(Bx0, Bx1, By0, By1, Bz0, Bz1);                 // c 2k+1
        }
        LOAD6(Bx0, Bx1, By0, By1, Bz0, Bz1, p);                 // c31
        COMP(Ax0, Ax1, Ay0, Ay1, Az0, Az1);                     // c30
        COMP(Bx0, Bx1, By0, By1, Bz0, Bz1);                     // c31

        if (chunk != 0) {
#pragma unroll
            for (int k = 0; k < 48; ++k)
                red[g * RSTRIDE + (chunk - 1) * 48 + k] = acc[k];
        }
    }
    __syncthreads();

    if (act && chunk == 0) {
#pragma unroll
        for (int k = 0; k < 48; ++k)
            acc[k] += red[g * RSTRIDE + k]
                    + red[g * RSTRIDE + 48 + k]
                    + red[g * RSTRIDE + 96 + k];

        float* op = out + (size_t)b * 8 * OPLANE + (size_t)i * WO + 6 * gc;
#pragma unroll
        for (int o = 0; o < 8; ++o) {
            float* q = op + (size_t)o * OPLANE;
            *reinterpret_cast<float2*>(q + 0) = make_float2(-acc[o * 6 + 0], -acc[o * 6 + 1]);
            *reinterpret_cast<float2*>(q + 2) = make_float2(-acc[o * 6 + 2], -acc[o * 6 + 3]);
            *reinterpret_cast<float2*>(q + 4) = make_float2(-acc[o * 6 + 4], -acc[o * 6 + 5]);
        }
    }
}

extern "C" void kernel_launch(void* const* d_in, const int* in_sizes, int n_in,
                              void* d_out, int out_size, void* d_ws, size_t ws_size,
                              hipStream_t stream) {
    const float* x = (const float*)d_in[0];
    float* out = (float*)d_out;
    nfp_sad_kernel<<<NBLK, 256, 0, stream>>>(x, out);
}